// Round 6
// baseline (215.940 us; speedup 1.0000x reference)
//
#include <hip/hip_runtime.h>

#define SPACE_TOK 63
#define INV_T 14.285714285714286f          /* 1/0.07 */
#define SA_SCALE 20.609929155556595f       /* log2(e)/0.07 ; also the static max bound */
#define LN2F 0.6931471805599453f

typedef __attribute__((ext_vector_type(8))) short bf16x8;
typedef __attribute__((ext_vector_type(4))) float f32x4;

// ---- workspace byte offsets ----
#define O_NSP    0                         /* 8 ints */
#define O_SPPOS  64                        /* 8*4096 ints */
#define O_CECM   131136                    /* 1024 f */
#define O_CEM    135232                    /* 1024 f */
#define O_CEC    139328                    /* 1024 f */
#define O_WPART  143424                    /* 4096 f */
#define O_WCNT   159808                    /* 256 f */
#define O_PEXP2  160832                    /* 8*4096 f */
#define O_PEXP3  291904                    /* 8*1024 f */
#define O_DIAG2  324672                    /* 4096 f */
#define O_DIAG3  341056                    /* 1024 f */
#define O_A2     345152
#define SZ_A2    (4096*128*2)
#define O_P2     (O_A2 + SZ_A2)
#define O_A3     (O_P2 + SZ_A2)
#define SZ_A3    (1024*128*2)
#define O_P3     (O_A3 + SZ_A3)

// fusedA dynamic LDS requirement: norm_body = 16896 + 1024 + 128 = 18048 B
// (R4 bug: launched with 17536 -> scl[] past allocation -> corrupted norms)
#define SMEM_A 18048

__device__ inline unsigned short f2bf(float x) {
  union { float f; unsigned int u; } c; c.f = x;
  unsigned int r = c.u + 0x7fffu + ((c.u >> 16) & 1u);
  return (unsigned short)(r >> 16);
}

// ================= dispatch A: scan(8) | norm2(256) | norm3(64) | ce(1024) =================
__device__ void scan_body(char* smem, const int* __restrict__ targets, char* ws, int b) {
  int tid = threadIdx.x;
  int* toks = (int*)smem;            // 4096 ints = 16384 B
  int* sc   = (int*)(smem + 16384);  // 256 ints  -> total 17408 B
  int* n_sp   = (int*)(ws + O_NSP);
  int* sp_pos = (int*)(ws + O_SPPOS);
  const int4* tb4 = (const int4*)(targets + b * 4096);
#pragma unroll
  for (int i = 0; i < 4; ++i) ((int4*)toks)[tid + 256 * i] = tb4[tid + 256 * i];
  __syncthreads();
  int base = tid * 16;
  int cnt = 0;
#pragma unroll
  for (int i = 0; i < 16; ++i) cnt += (toks[base + i] == SPACE_TOK);
  sc[tid] = cnt;
  __syncthreads();
  for (int off = 1; off < 256; off <<= 1) {
    int v = (tid >= off) ? sc[tid - off] : 0;
    __syncthreads();
    sc[tid] += v;
    __syncthreads();
  }
  int k = sc[tid] - cnt;  // exclusive prefix
  for (int i = 0; i < 16; ++i)
    if (toks[base + i] == SPACE_TOK) sp_pos[b * 4096 + (k++)] = base + i;
  if (tid == 255) n_sp[b] = sc[255];
}

// 32-l tile variant: 16896 + 1024 + 128 = 18048 B smem
__device__ void norm_body(char* smem, const float* __restrict__ emb, int L,
                          unsigned short* __restrict__ Abf, unsigned short* __restrict__ Pbf,
                          int b, int l0) {
  float (*tile)[33] = (float(*)[33])smem;                 // 128*33*4 = 16896 B
  float (*np8)[32]  = (float(*)[32])(smem + 16896);       // 8*32*4 = 1024 B
  float* scl        = (float*)(smem + 16896 + 1024);      // 128 B
  int tid = threadIdx.x;
  int lx = tid & 31, cq = tid >> 5;                       // 8 c-groups
  const float* eb = emb + (size_t)b * 128 * L + l0;
  for (int c = cq; c < 128; c += 8) tile[c][lx] = eb[(size_t)c * L + lx];
  __syncthreads();
  {
    float s = 0.f;
    for (int c = cq; c < 128; c += 8) { float x = tile[c][lx]; s += x * x; }
    np8[cq][lx] = s;
  }
  __syncthreads();
  if (tid < 32) {
    float t = 0.f;
#pragma unroll
    for (int g = 0; g < 8; ++g) t += np8[g][tid];
    float nrm = fmaxf(sqrtf(t), 1e-12f);
    scl[tid] = ((tid & 1) ? 1.0f : SA_SCALE) / nrm;  // even l -> anchor (scaled)
  }
  __syncthreads();
  int c = tid & 127, lh = tid >> 7;
  int half = L >> 1;
  for (int lp = lh; lp < 32; lp += 2) {
    int l = l0 + lp;
    int row = b * half + (l >> 1);
    unsigned short v = f2bf(tile[c][lp] * scl[lp]);
    ((l & 1) ? Pbf : Abf)[(size_t)row * 128 + c] = v;
  }
}

__device__ void ce_body(char* smem, const float* __restrict__ logits,
                        const int* __restrict__ targets, const float* __restrict__ mask,
                        char* ws, int cb) {
  int tid = threadIdx.x;
  int wave = tid >> 6, lane = tid & 63;
  int rbase = cb * 32 + wave * 8;
  float4 v[8];
  float mk[8];
  int tg[8];
#pragma unroll
  for (int rr = 0; rr < 8; ++rr) v[rr] = ((const float4*)logits)[(size_t)(rbase + rr) * 64 + lane];
#pragma unroll
  for (int rr = 0; rr < 8; ++rr) { tg[rr] = targets[rbase + rr]; mk[rr] = mask[rbase + rr]; }
  float aCM = 0.f, aM = 0.f, aC = 0.f;
#pragma unroll
  for (int rr = 0; rr < 8; ++rr) {
    float e = __expf(v[rr].x) + __expf(v[rr].y) + __expf(v[rr].z) + __expf(v[rr].w);
#pragma unroll
    for (int m = 1; m < 64; m <<= 1) e += __shfl_xor(e, m);
    int t = tg[rr];
    int q = t & 3;
    float sel = (q == 0) ? v[rr].x : (q == 1) ? v[rr].y : (q == 2) ? v[rr].z : v[rr].w;
    float xt = __shfl(sel, t >> 2);
    float ce = __logf(e) - xt;
    aCM += ce * mk[rr]; aM += mk[rr]; aC += ce;
  }
  float (*red)[3] = (float(*)[3])smem;
  if (lane == 0) { red[wave][0] = aCM; red[wave][1] = aM; red[wave][2] = aC; }
  __syncthreads();
  if (tid == 0) {
    ((float*)(ws + O_CECM))[cb] = red[0][0] + red[1][0] + red[2][0] + red[3][0];
    ((float*)(ws + O_CEM ))[cb] = red[0][1] + red[1][1] + red[2][1] + red[3][1];
    ((float*)(ws + O_CEC ))[cb] = red[0][2] + red[1][2] + red[2][2] + red[3][2];
  }
}

__global__ void __launch_bounds__(256) fusedA_kernel(const float* __restrict__ logits,
                                                     const int* __restrict__ targets,
                                                     const float* __restrict__ mask,
                                                     const float* __restrict__ c2,
                                                     const float* __restrict__ c3,
                                                     char* __restrict__ ws) {
  extern __shared__ char smem[];
  int bid = blockIdx.x;
  if (bid < 8) {
    scan_body(smem, targets, ws, bid);
  } else if (bid < 264) {
    int nb = bid - 8;
    norm_body(smem, c2, 1024, (unsigned short*)(ws + O_A2), (unsigned short*)(ws + O_P2),
              nb & 7, (nb >> 3) * 32);
  } else if (bid < 328) {
    int nb = bid - 264;
    norm_body(smem, c3, 256, (unsigned short*)(ws + O_A3), (unsigned short*)(ws + O_P3),
              nb & 7, (nb >> 3) * 32);
  } else {
    ce_body(smem, logits, targets, mask, ws, bid - 328);
  }
}

// ================= dispatch B: nce2(2048) | nce3(512) | word(4096) =================
// J-split partial: block = 16-row I-tile x (sliceJ)-wide J-slice; writes partial
// sum-of-exp2 per row + diag (only from the slice owning the diagonal tile).
__device__ void nce_body(char* smem, const unsigned short* __restrict__ A,
                         const unsigned short* __restrict__ P, int n, int sliceJ,
                         int blk_i, int s, float* __restrict__ pexp,
                         float* __restrict__ diag) {
  int tid = threadIdx.x;
  int wave = tid >> 6, lane = tid & 63;
  int col = lane & 15, quad = lane >> 4;
  int I0 = blk_i * 16;
  const unsigned short* Ap = A + (size_t)(I0 + col) * 128 + quad * 8;
  bf16x8 a0 = *(const bf16x8*)(Ap);
  bf16x8 a1 = *(const bf16x8*)(Ap + 32);
  bf16x8 a2 = *(const bf16x8*)(Ap + 64);
  bf16x8 a3 = *(const bf16x8*)(Ap + 96);
  float rl0 = 0.f, rl1 = 0.f, rl2 = 0.f, rl3 = 0.f;
  float dcap = 0.f;
  int perW = sliceJ >> 2;                 // J per wave
  int J0w = s * sliceJ + wave * perW, Jend = J0w + perW;
#pragma unroll 2
  for (int J = J0w; J < Jend; J += 16) {
    const unsigned short* Pp = P + (size_t)(J + col) * 128 + quad * 8;
    bf16x8 b0 = *(const bf16x8*)(Pp);
    bf16x8 b1 = *(const bf16x8*)(Pp + 32);
    bf16x8 b2 = *(const bf16x8*)(Pp + 64);
    bf16x8 b3 = *(const bf16x8*)(Pp + 96);
    f32x4 cfr = {0.f, 0.f, 0.f, 0.f};
    cfr = __builtin_amdgcn_mfma_f32_16x16x32_bf16(a0, b0, cfr, 0, 0, 0);
    cfr = __builtin_amdgcn_mfma_f32_16x16x32_bf16(a1, b1, cfr, 0, 0, 0);
    cfr = __builtin_amdgcn_mfma_f32_16x16x32_bf16(a2, b2, cfr, 0, 0, 0);
    cfr = __builtin_amdgcn_mfma_f32_16x16x32_bf16(a3, b3, cfr, 0, 0, 0);
    rl0 += exp2f(cfr[0] - SA_SCALE);
    rl1 += exp2f(cfr[1] - SA_SCALE);
    rl2 += exp2f(cfr[2] - SA_SCALE);
    rl3 += exp2f(cfr[3] - SA_SCALE);
    if (J == I0) {                        // diagonal tile
      int r = col - (quad << 2);
      if (r == 0) dcap = cfr[0];
      else if (r == 1) dcap = cfr[1];
      else if (r == 2) dcap = cfr[2];
      else if (r == 3) dcap = cfr[3];
    }
  }
  float (*part)[16][16] = (float(*)[16][16])smem;          // 4096 B
  float (*dpart)[16]    = (float(*)[16])(smem + 4096);     // 256 B
  part[wave][(quad << 2) + 0][col] = rl0;
  part[wave][(quad << 2) + 1][col] = rl1;
  part[wave][(quad << 2) + 2][col] = rl2;
  part[wave][(quad << 2) + 3][col] = rl3;
  if (quad == (col >> 2)) dpart[wave][col] = dcap;
  __syncthreads();
  {
    int rrow = tid >> 4, cc = tid & 15;
    float sv = 0.f, d = 0.f;
#pragma unroll
    for (int w = 0; w < 4; ++w) { sv += part[w][rrow][cc]; d += dpart[w][rrow]; }
#pragma unroll
    for (int m = 1; m < 16; m <<= 1) sv += __shfl_xor(sv, m);
    if (cc == 0) {
      pexp[I0 + rrow] = sv;
      if (I0 >= s * sliceJ && I0 < (s + 1) * sliceJ) diag[I0 + rrow] = d;
    }
  }
}

__device__ void word_body(char* smem, const float* __restrict__ wp,
                          const float* __restrict__ cf, char* ws, int w) {
  int b = w & 7, y = (w >> 3) & 31, z = w >> 8;
  int ns = ((const int*)(ws + O_NSP))[b];
  const int* sp_pos = (const int*)(ws + O_SPPOS);
  int wave = threadIdx.x >> 6, lane = threadIdx.x & 63;
  int dbase = z * 32 + wave * 8;
  float myacc = 0.f;
  float lcnt = 0.f;
  for (int k = 1 + y; k <= ns - 1; k += 32) {
    int t0 = sp_pos[b * 4096 + k - 1];
    int t1 = sp_pos[b * 4096 + k];
    int cnt = t1 - t0 - 1;
    if (cnt <= 0) continue;
    lcnt += 1.0f;                        // uniform across block
    int wpos = t0 >> 1;
    float invc = 1.0f / (float)cnt;
    const float* r0 = cf + ((size_t)(b * 512 + dbase)) * 4096;
    int c0 = (t0 + 1) >> 2;
    int c1 = (t1 + 3) >> 2;
    float s0 = 0.f, s1 = 0.f, s2 = 0.f, s3 = 0.f, s4 = 0.f, s5 = 0.f, s6 = 0.f, s7 = 0.f;
    for (int c = c0 + lane; c < c1; c += 64) {
      int tb = c << 2;
      float4 v0 = *(const float4*)(r0 + 0 * 4096 + tb);
      float4 v1 = *(const float4*)(r0 + 1 * 4096 + tb);
      float4 v2 = *(const float4*)(r0 + 2 * 4096 + tb);
      float4 v3 = *(const float4*)(r0 + 3 * 4096 + tb);
      float4 v4 = *(const float4*)(r0 + 4 * 4096 + tb);
      float4 v5 = *(const float4*)(r0 + 5 * 4096 + tb);
      float4 v6 = *(const float4*)(r0 + 6 * 4096 + tb);
      float4 v7 = *(const float4*)(r0 + 7 * 4096 + tb);
      float m0 = (tb + 0 > t0 && tb + 0 < t1) ? 1.f : 0.f;
      float m1 = (tb + 1 > t0 && tb + 1 < t1) ? 1.f : 0.f;
      float m2 = (tb + 2 > t0 && tb + 2 < t1) ? 1.f : 0.f;
      float m3 = (tb + 3 > t0 && tb + 3 < t1) ? 1.f : 0.f;
      s0 += v0.x * m0 + v0.y * m1 + v0.z * m2 + v0.w * m3;
      s1 += v1.x * m0 + v1.y * m1 + v1.z * m2 + v1.w * m3;
      s2 += v2.x * m0 + v2.y * m1 + v2.z * m2 + v2.w * m3;
      s3 += v3.x * m0 + v3.y * m1 + v3.z * m2 + v3.w * m3;
      s4 += v4.x * m0 + v4.y * m1 + v4.z * m2 + v4.w * m3;
      s5 += v5.x * m0 + v5.y * m1 + v5.z * m2 + v5.w * m3;
      s6 += v6.x * m0 + v6.y * m1 + v6.z * m2 + v6.w * m3;
      s7 += v7.x * m0 + v7.y * m1 + v7.z * m2 + v7.w * m3;
    }
#pragma unroll
    for (int m = 1; m < 64; m <<= 1) {
      s0 += __shfl_xor(s0, m); s1 += __shfl_xor(s1, m);
      s2 += __shfl_xor(s2, m); s3 += __shfl_xor(s3, m);
      s4 += __shfl_xor(s4, m); s5 += __shfl_xor(s5, m);
      s6 += __shfl_xor(s6, m); s7 += __shfl_xor(s7, m);
    }
    if (lane < 8) {
      float sv = (lane == 0) ? s0 : (lane == 1) ? s1 : (lane == 2) ? s2 : (lane == 3) ? s3
               : (lane == 4) ? s4 : (lane == 5) ? s5 : (lane == 6) ? s6 : s7;
      float mean = sv * invc;
      float pred = wp[((size_t)(b * 512 + dbase + lane)) * 2048 + wpos];
      float diff = pred - mean;
      myacc += diff * diff;
    }
  }
#pragma unroll
  for (int m = 1; m < 8; m <<= 1) myacc += __shfl_xor(myacc, m);
  float* wacc = (float*)smem;
  if (lane == 0) wacc[wave] = myacc;
  __syncthreads();
  if (threadIdx.x == 0) {
    ((float*)(ws + O_WPART))[w] = (wacc[0] + wacc[1] + wacc[2] + wacc[3]) * (1.0f / 512.0f);
    if (z == 0) ((float*)(ws + O_WCNT))[w] = lcnt;
  }
}

__global__ void __launch_bounds__(256) fusedB_kernel(const float* __restrict__ wp,
                                                     const float* __restrict__ cf,
                                                     char* __restrict__ ws) {
  extern __shared__ char smem[];
  int bid = blockIdx.x;
  if (bid < 2048) {
    nce_body(smem, (const unsigned short*)(ws + O_A2), (const unsigned short*)(ws + O_P2),
             4096, 512, bid >> 3, bid & 7,
             (float*)(ws + O_PEXP2) + (bid & 7) * 4096, (float*)(ws + O_DIAG2));
  } else if (bid < 2560) {
    int nb = bid - 2048;
    nce_body(smem, (const unsigned short*)(ws + O_A3), (const unsigned short*)(ws + O_P3),
             1024, 128, nb >> 3, nb & 7,
             (float*)(ws + O_PEXP3) + (nb & 7) * 1024, (float*)(ws + O_DIAG3));
  } else {
    word_body(smem, wp, cf, ws, bid - 2560);
  }
}

// ================= dispatch C: final tree-reduce + combine =================
__global__ void __launch_bounds__(256) final_kernel(const char* __restrict__ ws,
                                                    float* __restrict__ out) {
  int tid = threadIdx.x;
  int wave = tid >> 6, lane = tid & 63;
  const float* cecm  = (const float*)(ws + O_CECM);
  const float* cem   = (const float*)(ws + O_CEM);
  const float* cec   = (const float*)(ws + O_CEC);
  const float* wpart = (const float*)(ws + O_WPART);
  const float* wcnt  = (const float*)(ws + O_WCNT);
  const float* p2    = (const float*)(ws + O_PEXP2);
  const float* p3    = (const float*)(ws + O_PEXP3);
  const float* dg2   = (const float*)(ws + O_DIAG2);
  const float* dg3   = (const float*)(ws + O_DIAG3);
  float v[7] = {0.f, 0.f, 0.f, 0.f, 0.f, 0.f, 0.f};
  for (int i = tid; i < 1024; i += 256) { v[0] += cecm[i]; v[1] += cem[i]; v[2] += cec[i]; }
  for (int i = tid; i < 4096; i += 256) v[3] += wpart[i];
  v[4] = wcnt[tid];
  for (int r = tid; r < 4096; r += 256) {
    float S = 0.f;
#pragma unroll
    for (int s = 0; s < 8; ++s) S += p2[s * 4096 + r];
    v[5] += INV_T + __logf(S) - LN2F * dg2[r];
  }
  for (int r = tid; r < 1024; r += 256) {
    float S = 0.f;
#pragma unroll
    for (int s = 0; s < 8; ++s) S += p3[s * 1024 + r];
    v[6] += INV_T + __logf(S) - LN2F * dg3[r];
  }
#pragma unroll
  for (int j = 0; j < 7; ++j) {
    float x = v[j];
#pragma unroll
    for (int m = 1; m < 64; m <<= 1) x += __shfl_xor(x, m);
    v[j] = x;
  }
  __shared__ float fr[4][7];
  if (lane == 0)
#pragma unroll
    for (int j = 0; j < 7; ++j) fr[wave][j] = v[j];
  __syncthreads();
  if (tid == 0) {
    float s[7];
#pragma unroll
    for (int j = 0; j < 7; ++j) s[j] = fr[0][j] + fr[1][j] + fr[2][j] + fr[3][j];
    float n = s[1];
    float charL = (n > 0.f) ? (s[0] / fmaxf(n, 1.f)) : (s[2] / 32768.0f);
    float wordL = (s[4] > 0.f) ? (s[3] / fmaxf(s[4], 1.f)) : 0.f;
    out[0] = charL + 0.5f * wordL + 0.1f * (s[5] / 4096.0f) + 0.1f * (s[6] / 1024.0f);
  }
}

extern "C" void kernel_launch(void* const* d_in, const int* in_sizes, int n_in,
                              void* d_out, int out_size, void* d_ws, size_t ws_size,
                              hipStream_t stream) {
  (void)in_sizes; (void)n_in; (void)out_size; (void)ws_size;
  const float* logits        = (const float*)d_in[0];
  const float* word_preds    = (const float*)d_in[1];
  const float* char_features = (const float*)d_in[2];
  const float* c2            = (const float*)d_in[3];
  const float* c3            = (const float*)d_in[4];
  const int*   targets       = (const int*)d_in[5];
  const float* mask          = (const float*)d_in[6];
  float* out = (float*)d_out;
  char* ws = (char*)d_ws;

  fusedA_kernel<<<1352, 256, SMEM_A, stream>>>(logits, targets, mask, c2, c3, ws);
  fusedB_kernel<<<6656, 256, 4480, stream>>>(word_preds, char_features, ws);
  final_kernel<<<1, 256, 0, stream>>>(ws, out);
}

// Round 7
// 212.544 us; speedup vs baseline: 1.0160x; 1.0160x over previous
//
#include <hip/hip_runtime.h>

#define SPACE_TOK 63
#define INV_T 14.285714285714286f          /* 1/0.07 */
#define SA_SCALE 20.609929155556595f       /* log2(e)/0.07 ; also the static max bound */
#define LN2F 0.6931471805599453f

typedef __attribute__((ext_vector_type(8))) short bf16x8;
typedef __attribute__((ext_vector_type(4))) float f32x4;

// ---- workspace byte offsets ----
#define O_CECM   0                         /* 1024 f */
#define O_CEM    4096                      /* 1024 f */
#define O_CEC    8192                      /* 1024 f */
#define O_WPART  12288                     /* 512 f */
#define O_WCNT   14336                     /* 32 f */
#define O_PEXP2  14464                     /* 8*4096 f */
#define O_DIAG2  145536                    /* 4096 f */
#define O_PEXP3  161920                    /* 8*1024 f */
#define O_DIAG3  194688                    /* 1024 f */
#define O_A2     198784
#define SZ_A2    (4096*128*2)
#define O_P2     (O_A2 + SZ_A2)
#define O_A3     (O_P2 + SZ_A2)
#define SZ_A3    (1024*128*2)
#define O_P3     (O_A3 + SZ_A3)

#define SMEM_A 18048   /* norm_body: 16896 + 1024 + 128 */

__device__ inline unsigned short f2bf(float x) {
  union { float f; unsigned int u; } c; c.f = x;
  unsigned int r = c.u + 0x7fffu + ((c.u >> 16) & 1u);
  return (unsigned short)(r >> 16);
}

// ================= dispatch A: norm2(256) | norm3(64) | ce(1024) =================
__device__ void norm_body(char* smem, const float* __restrict__ emb, int L,
                          unsigned short* __restrict__ Abf, unsigned short* __restrict__ Pbf,
                          int b, int l0) {
  float (*tile)[33] = (float(*)[33])smem;                 // 128*33*4 = 16896 B
  float (*np8)[32]  = (float(*)[32])(smem + 16896);       // 1024 B
  float* scl        = (float*)(smem + 16896 + 1024);      // 128 B
  int tid = threadIdx.x;
  int lx = tid & 31, cq = tid >> 5;
  const float* eb = emb + (size_t)b * 128 * L + l0;
  for (int c = cq; c < 128; c += 8) tile[c][lx] = eb[(size_t)c * L + lx];
  __syncthreads();
  {
    float s = 0.f;
    for (int c = cq; c < 128; c += 8) { float x = tile[c][lx]; s += x * x; }
    np8[cq][lx] = s;
  }
  __syncthreads();
  if (tid < 32) {
    float t = 0.f;
#pragma unroll
    for (int g = 0; g < 8; ++g) t += np8[g][tid];
    float nrm = fmaxf(sqrtf(t), 1e-12f);
    scl[tid] = ((tid & 1) ? 1.0f : SA_SCALE) / nrm;  // even l -> anchor (scaled)
  }
  __syncthreads();
  int c = tid & 127, lh = tid >> 7;
  int half = L >> 1;
  for (int lp = lh; lp < 32; lp += 2) {
    int l = l0 + lp;
    int row = b * half + (l >> 1);
    unsigned short v = f2bf(tile[c][lp] * scl[lp]);
    ((l & 1) ? Pbf : Abf)[(size_t)row * 128 + c] = v;
  }
}

__device__ void ce_body(char* smem, const float* __restrict__ logits,
                        const int* __restrict__ targets, const float* __restrict__ mask,
                        char* ws, int cb) {
  int tid = threadIdx.x;
  int wave = tid >> 6, lane = tid & 63;
  int rbase = cb * 32 + wave * 8;
  float4 v[8];
  float mk[8];
  int tg[8];
#pragma unroll
  for (int rr = 0; rr < 8; ++rr) v[rr] = ((const float4*)logits)[(size_t)(rbase + rr) * 64 + lane];
#pragma unroll
  for (int rr = 0; rr < 8; ++rr) { tg[rr] = targets[rbase + rr]; mk[rr] = mask[rbase + rr]; }
  float aCM = 0.f, aM = 0.f, aC = 0.f;
#pragma unroll
  for (int rr = 0; rr < 8; ++rr) {
    float e = __expf(v[rr].x) + __expf(v[rr].y) + __expf(v[rr].z) + __expf(v[rr].w);
#pragma unroll
    for (int m = 1; m < 64; m <<= 1) e += __shfl_xor(e, m);
    int t = tg[rr];
    int q = t & 3;
    float sel = (q == 0) ? v[rr].x : (q == 1) ? v[rr].y : (q == 2) ? v[rr].z : v[rr].w;
    float xt = __shfl(sel, t >> 2);
    float ce = __logf(e) - xt;
    aCM += ce * mk[rr]; aM += mk[rr]; aC += ce;
  }
  float (*red)[3] = (float(*)[3])smem;
  if (lane == 0) { red[wave][0] = aCM; red[wave][1] = aM; red[wave][2] = aC; }
  __syncthreads();
  if (tid == 0) {
    ((float*)(ws + O_CECM))[cb] = red[0][0] + red[1][0] + red[2][0] + red[3][0];
    ((float*)(ws + O_CEM ))[cb] = red[0][1] + red[1][1] + red[2][1] + red[3][1];
    ((float*)(ws + O_CEC ))[cb] = red[0][2] + red[1][2] + red[2][2] + red[3][2];
  }
}

__global__ void __launch_bounds__(256) fusedA_kernel(const float* __restrict__ logits,
                                                     const int* __restrict__ targets,
                                                     const float* __restrict__ mask,
                                                     const float* __restrict__ c2,
                                                     const float* __restrict__ c3,
                                                     char* __restrict__ ws) {
  extern __shared__ char smem[];
  int bid = blockIdx.x;
  if (bid < 256) {
    norm_body(smem, c2, 1024, (unsigned short*)(ws + O_A2), (unsigned short*)(ws + O_P2),
              bid & 7, (bid >> 3) * 32);
  } else if (bid < 320) {
    int nb = bid - 256;
    norm_body(smem, c3, 256, (unsigned short*)(ws + O_A3), (unsigned short*)(ws + O_P3),
              nb & 7, (nb >> 3) * 32);
  } else {
    ce_body(smem, logits, targets, mask, ws, bid - 320);
  }
}

// ================= dispatch B: word, self-contained (b, tq, z) = 8*4*16 = 512 =================
__global__ void __launch_bounds__(256) word_kernel(const float* __restrict__ wp,
                                                   const float* __restrict__ cf,
                                                   const int* __restrict__ targets,
                                                   char* __restrict__ ws) {
  __shared__ int sc[256];
  __shared__ int splist[1024];
  __shared__ int snext_sh;
  __shared__ float wacc[4];
  int tid = threadIdx.x;
  int w = blockIdx.x;
  int z = w & 15, tq = (w >> 4) & 3, b = w >> 6;
  const int* tb = targets + b * 4096;
  int tbase = tq * 1024;
  // stage & flag: each thread owns 4 consecutive tokens
  int4 tok = ((const int4*)(tb + tbase))[tid];
  int f0 = (tok.x == SPACE_TOK), f1 = (tok.y == SPACE_TOK),
      f2 = (tok.z == SPACE_TOK), f3 = (tok.w == SPACE_TOK);
  int cnt = f0 + f1 + f2 + f3;
  sc[tid] = cnt;
  __syncthreads();
  for (int off = 1; off < 256; off <<= 1) {
    int v = (tid >= off) ? sc[tid - off] : 0;
    __syncthreads();
    sc[tid] += v;
    __syncthreads();
  }
  int base = sc[tid] - cnt;  // exclusive prefix
  int p = tbase + tid * 4;
  if (f0) splist[base++] = p;
  if (f1) splist[base++] = p + 1;
  if (f2) splist[base++] = p + 2;
  if (f3) splist[base++] = p + 3;
  int m = sc[255];           // spaces in this quarter (uniform)
  if (tid == 0) snext_sh = -1;
  __syncthreads();           // covers splist writes, m read, snext init
  if (m > 0) {               // lookahead: first space at t >= tbase+1024
    for (int wstart = tbase + 1024; wstart < 4096 && snext_sh < 0; wstart += 1024) {
      int t = wstart + tid * 4;
      int4 tk = ((const int4*)tb)[t >> 2];
      int found = 0x7fffffff;
      if (tk.x == SPACE_TOK) found = t;
      else if (tk.y == SPACE_TOK) found = t + 1;
      else if (tk.z == SPACE_TOK) found = t + 2;
      else if (tk.w == SPACE_TOK) found = t + 3;
#pragma unroll
      for (int mm = 1; mm < 64; mm <<= 1) found = min(found, __shfl_xor(found, mm));
      if ((tid & 63) == 0) sc[tid >> 6] = found;
      __syncthreads();
      if (tid == 0) {
        int f = min(min(sc[0], sc[1]), min(sc[2], sc[3]));
        if (f != 0x7fffffff) snext_sh = f;
      }
      __syncthreads();
    }
  }
  int snext = snext_sh;
  int wave = tid >> 6, lane = tid & 63;
  int dbase = z * 32 + wave * 8;
  const float* r0 = cf + ((size_t)(b * 512 + dbase)) * 4096;
  float myacc = 0.f;
  float lcnt = 0.f;
  for (int i = 0; i < m; ++i) {
    int t0 = splist[i];
    int t1 = (i + 1 < m) ? splist[i + 1] : snext;
    if (t1 < 0) break;                    // left space is the global last -> invalid
    int seglen = t1 - t0 - 1;
    if (seglen <= 0) continue;
    lcnt += 1.0f;
    int wpos = t0 >> 1;
    float invc = 1.0f / (float)seglen;
    int c0 = (t0 + 1) >> 2;
    int c1 = (t1 + 3) >> 2;
    float s0 = 0.f, s1 = 0.f, s2 = 0.f, s3 = 0.f, s4 = 0.f, s5 = 0.f, s6 = 0.f, s7 = 0.f;
    for (int c = c0 + lane; c < c1; c += 64) {
      int tbp = c << 2;
      float4 v0 = *(const float4*)(r0 + 0 * 4096 + tbp);
      float4 v1 = *(const float4*)(r0 + 1 * 4096 + tbp);
      float4 v2 = *(const float4*)(r0 + 2 * 4096 + tbp);
      float4 v3 = *(const float4*)(r0 + 3 * 4096 + tbp);
      float4 v4 = *(const float4*)(r0 + 4 * 4096 + tbp);
      float4 v5 = *(const float4*)(r0 + 5 * 4096 + tbp);
      float4 v6 = *(const float4*)(r0 + 6 * 4096 + tbp);
      float4 v7 = *(const float4*)(r0 + 7 * 4096 + tbp);
      float m0 = (tbp + 0 > t0 && tbp + 0 < t1) ? 1.f : 0.f;
      float m1 = (tbp + 1 > t0 && tbp + 1 < t1) ? 1.f : 0.f;
      float m2 = (tbp + 2 > t0 && tbp + 2 < t1) ? 1.f : 0.f;
      float m3 = (tbp + 3 > t0 && tbp + 3 < t1) ? 1.f : 0.f;
      s0 += v0.x * m0 + v0.y * m1 + v0.z * m2 + v0.w * m3;
      s1 += v1.x * m0 + v1.y * m1 + v1.z * m2 + v1.w * m3;
      s2 += v2.x * m0 + v2.y * m1 + v2.z * m2 + v2.w * m3;
      s3 += v3.x * m0 + v3.y * m1 + v3.z * m2 + v3.w * m3;
      s4 += v4.x * m0 + v4.y * m1 + v4.z * m2 + v4.w * m3;
      s5 += v5.x * m0 + v5.y * m1 + v5.z * m2 + v5.w * m3;
      s6 += v6.x * m0 + v6.y * m1 + v6.z * m2 + v6.w * m3;
      s7 += v7.x * m0 + v7.y * m1 + v7.z * m2 + v7.w * m3;
    }
#pragma unroll
    for (int mm = 1; mm < 64; mm <<= 1) {
      s0 += __shfl_xor(s0, mm); s1 += __shfl_xor(s1, mm);
      s2 += __shfl_xor(s2, mm); s3 += __shfl_xor(s3, mm);
      s4 += __shfl_xor(s4, mm); s5 += __shfl_xor(s5, mm);
      s6 += __shfl_xor(s6, mm); s7 += __shfl_xor(s7, mm);
    }
    if (lane < 8) {
      float sv = (lane == 0) ? s0 : (lane == 1) ? s1 : (lane == 2) ? s2 : (lane == 3) ? s3
               : (lane == 4) ? s4 : (lane == 5) ? s5 : (lane == 6) ? s6 : s7;
      float mean = sv * invc;
      float pred = wp[((size_t)(b * 512 + dbase + lane)) * 2048 + wpos];
      float diff = pred - mean;
      myacc += diff * diff;
    }
  }
#pragma unroll
  for (int mm = 1; mm < 8; mm <<= 1) myacc += __shfl_xor(myacc, mm);
  if (lane == 0) wacc[wave] = myacc;
  __syncthreads();
  if (tid == 0) {
    ((float*)(ws + O_WPART))[w] = (wacc[0] + wacc[1] + wacc[2] + wacc[3]) * (1.0f / 512.0f);
    if (z == 0) ((float*)(ws + O_WCNT))[w >> 4] = lcnt;   // one count per (b,tq)
  }
}

// ================= dispatch C: nce2(2048) | nce3(512), J-split x8 =================
__device__ void nce_body(char* smem, const unsigned short* __restrict__ A,
                         const unsigned short* __restrict__ P, int n, int sliceJ,
                         int blk_i, int s, float* __restrict__ pexp,
                         float* __restrict__ diag) {
  int tid = threadIdx.x;
  int wave = tid >> 6, lane = tid & 63;
  int col = lane & 15, quad = lane >> 4;
  int I0 = blk_i * 16;
  const unsigned short* Ap = A + (size_t)(I0 + col) * 128 + quad * 8;
  bf16x8 a0 = *(const bf16x8*)(Ap);
  bf16x8 a1 = *(const bf16x8*)(Ap + 32);
  bf16x8 a2 = *(const bf16x8*)(Ap + 64);
  bf16x8 a3 = *(const bf16x8*)(Ap + 96);
  float rl0 = 0.f, rl1 = 0.f, rl2 = 0.f, rl3 = 0.f;
  float dcap = 0.f;
  int perW = sliceJ >> 2;
  int J0w = s * sliceJ + wave * perW, Jend = J0w + perW;
#pragma unroll 2
  for (int J = J0w; J < Jend; J += 16) {
    const unsigned short* Pp = P + (size_t)(J + col) * 128 + quad * 8;
    bf16x8 b0 = *(const bf16x8*)(Pp);
    bf16x8 b1 = *(const bf16x8*)(Pp + 32);
    bf16x8 b2 = *(const bf16x8*)(Pp + 64);
    bf16x8 b3 = *(const bf16x8*)(Pp + 96);
    f32x4 cfr = {0.f, 0.f, 0.f, 0.f};
    cfr = __builtin_amdgcn_mfma_f32_16x16x32_bf16(a0, b0, cfr, 0, 0, 0);
    cfr = __builtin_amdgcn_mfma_f32_16x16x32_bf16(a1, b1, cfr, 0, 0, 0);
    cfr = __builtin_amdgcn_mfma_f32_16x16x32_bf16(a2, b2, cfr, 0, 0, 0);
    cfr = __builtin_amdgcn_mfma_f32_16x16x32_bf16(a3, b3, cfr, 0, 0, 0);
    rl0 += exp2f(cfr[0] - SA_SCALE);
    rl1 += exp2f(cfr[1] - SA_SCALE);
    rl2 += exp2f(cfr[2] - SA_SCALE);
    rl3 += exp2f(cfr[3] - SA_SCALE);
    if (J == I0) {
      int r = col - (quad << 2);
      if (r == 0) dcap = cfr[0];
      else if (r == 1) dcap = cfr[1];
      else if (r == 2) dcap = cfr[2];
      else if (r == 3) dcap = cfr[3];
    }
  }
  float (*part)[16][16] = (float(*)[16][16])smem;
  float (*dpart)[16]    = (float(*)[16])(smem + 4096);
  part[wave][(quad << 2) + 0][col] = rl0;
  part[wave][(quad << 2) + 1][col] = rl1;
  part[wave][(quad << 2) + 2][col] = rl2;
  part[wave][(quad << 2) + 3][col] = rl3;
  if (quad == (col >> 2)) dpart[wave][col] = dcap;
  __syncthreads();
  {
    int rrow = tid >> 4, cc = tid & 15;
    float sv = 0.f, d = 0.f;
#pragma unroll
    for (int ww = 0; ww < 4; ++ww) { sv += part[ww][rrow][cc]; d += dpart[ww][rrow]; }
#pragma unroll
    for (int mm = 1; mm < 16; mm <<= 1) sv += __shfl_xor(sv, mm);
    if (cc == 0) {
      pexp[I0 + rrow] = sv;
      if (I0 >= s * sliceJ && I0 < (s + 1) * sliceJ) diag[I0 + rrow] = d;
    }
  }
}

__global__ void __launch_bounds__(256) fusedC_kernel(char* __restrict__ ws) {
  extern __shared__ char smem[];
  int bid = blockIdx.x;
  if (bid < 2048) {
    nce_body(smem, (const unsigned short*)(ws + O_A2), (const unsigned short*)(ws + O_P2),
             4096, 512, bid >> 3, bid & 7,
             (float*)(ws + O_PEXP2) + (bid & 7) * 4096, (float*)(ws + O_DIAG2));
  } else {
    int nb = bid - 2048;
    nce_body(smem, (const unsigned short*)(ws + O_A3), (const unsigned short*)(ws + O_P3),
             1024, 128, nb >> 3, nb & 7,
             (float*)(ws + O_PEXP3) + (nb & 7) * 1024, (float*)(ws + O_DIAG3));
  }
}

// ================= dispatch D: final tree-reduce + combine (vectorized) =================
__global__ void __launch_bounds__(256) final_kernel(const char* __restrict__ ws,
                                                    float* __restrict__ out) {
  int tid = threadIdx.x;
  int wave = tid >> 6, lane = tid & 63;
  float v[7] = {0.f, 0.f, 0.f, 0.f, 0.f, 0.f, 0.f};
  {
    float4 a = ((const float4*)(ws + O_CECM))[tid];
    float4 bb = ((const float4*)(ws + O_CEM))[tid];
    float4 c = ((const float4*)(ws + O_CEC))[tid];
    v[0] = a.x + a.y + a.z + a.w;
    v[1] = bb.x + bb.y + bb.z + bb.w;
    v[2] = c.x + c.y + c.z + c.w;
  }
  if (tid < 128) {
    float4 wv = ((const float4*)(ws + O_WPART))[tid];
    v[3] = wv.x + wv.y + wv.z + wv.w;
  }
  if (tid < 32) v[4] = ((const float*)(ws + O_WCNT))[tid];
  for (int r4 = tid; r4 < 1024; r4 += 256) {          // pexp2: 4096 rows as float4
    float4 S = {0.f, 0.f, 0.f, 0.f};
#pragma unroll
    for (int s = 0; s < 8; ++s) {
      float4 pv = ((const float4*)(ws + O_PEXP2))[s * 1024 + r4];
      S.x += pv.x; S.y += pv.y; S.z += pv.z; S.w += pv.w;
    }
    float4 dg = ((const float4*)(ws + O_DIAG2))[r4];
    v[5] += 4.0f * INV_T + __logf(S.x) + __logf(S.y) + __logf(S.z) + __logf(S.w)
            - LN2F * (dg.x + dg.y + dg.z + dg.w);
  }
  if (tid < 256) {                                     // pexp3: 1024 rows as float4
    int r4 = tid;
    float4 S = {0.f, 0.f, 0.f, 0.f};
#pragma unroll
    for (int s = 0; s < 8; ++s) {
      float4 pv = ((const float4*)(ws + O_PEXP3))[s * 256 + r4];
      S.x += pv.x; S.y += pv.y; S.z += pv.z; S.w += pv.w;
    }
    float4 dg = ((const float4*)(ws + O_DIAG3))[r4];
    v[6] = 4.0f * INV_T + __logf(S.x) + __logf(S.y) + __logf(S.z) + __logf(S.w)
           - LN2F * (dg.x + dg.y + dg.z + dg.w);
  }
#pragma unroll
  for (int j = 0; j < 7; ++j) {
    float x = v[j];
#pragma unroll
    for (int mm = 1; mm < 64; mm <<= 1) x += __shfl_xor(x, mm);
    v[j] = x;
  }
  __shared__ float fr[4][7];
  if (lane == 0)
#pragma unroll
    for (int j = 0; j < 7; ++j) fr[wave][j] = v[j];
  __syncthreads();
  if (tid == 0) {
    float s[7];
#pragma unroll
    for (int j = 0; j < 7; ++j) s[j] = fr[0][j] + fr[1][j] + fr[2][j] + fr[3][j];
    float n = s[1];
    float charL = (n > 0.f) ? (s[0] / fmaxf(n, 1.f)) : (s[2] / 32768.0f);
    float wordL = (s[4] > 0.f) ? (s[3] / fmaxf(s[4], 1.f)) : 0.f;
    out[0] = charL + 0.5f * wordL + 0.1f * (s[5] / 4096.0f) + 0.1f * (s[6] / 1024.0f);
  }
}

extern "C" void kernel_launch(void* const* d_in, const int* in_sizes, int n_in,
                              void* d_out, int out_size, void* d_ws, size_t ws_size,
                              hipStream_t stream) {
  (void)in_sizes; (void)n_in; (void)out_size; (void)ws_size;
  const float* logits        = (const float*)d_in[0];
  const float* word_preds    = (const float*)d_in[1];
  const float* char_features = (const float*)d_in[2];
  const float* c2            = (const float*)d_in[3];
  const float* c3            = (const float*)d_in[4];
  const int*   targets       = (const int*)d_in[5];
  const float* mask          = (const float*)d_in[6];
  float* out = (float*)d_out;
  char* ws = (char*)d_ws;

  fusedA_kernel<<<1344, 256, SMEM_A, stream>>>(logits, targets, mask, c2, c3, ws);
  word_kernel<<<512, 256, 0, stream>>>(word_preds, char_features, targets, ws);
  fusedC_kernel<<<2560, 256, 4480, stream>>>(ws);
  final_kernel<<<1, 256, 0, stream>>>(ws, out);
}

// Round 8
// 174.257 us; speedup vs baseline: 1.2392x; 1.2197x over previous
//
#include <hip/hip_runtime.h>

#define SPACE_TOK 63
#define INV_T 14.285714285714286f          /* 1/0.07 */
#define SA_SCALE 20.609929155556595f       /* log2(e)/0.07 ; also the static max bound */
#define LN2F 0.6931471805599453f

typedef __attribute__((ext_vector_type(8))) short bf16x8;
typedef __attribute__((ext_vector_type(4))) float f32x4;

// ---- workspace byte offsets ----
#define O_CECM   0                         /* 1024 f */
#define O_CEM    4096                      /* 1024 f */
#define O_CEC    8192                      /* 1024 f */
#define O_WPART  12288                     /* 512 f */
#define O_WCNT   14336                     /* 32 f */
#define O_PEXP2  14464                     /* 8*4096 f -> ends 145536 */
#define O_DIAG2  145536                    /* 4096 f  -> 161920 */
#define O_PEXP3  161920                    /* 8*1024 f -> 194688 */
#define O_DIAG3  194688                    /* 1024 f  -> 198784 */
#define O_A2     198848                    /* swizzled bf16 */
#define SZ_A2    (4096*128*2)
#define O_P2     (O_A2 + SZ_A2)
#define O_A3     (O_P2 + SZ_A2)
#define SZ_A3    (1024*128*2)
#define O_P3     (O_A3 + SZ_A3)

#define SMEM_A 18048   /* norm_body: 16896 + 1024 + 128 */
#define SMEM_B 5632    /* max(word 5140, nce 4608, ce 48) */

__device__ inline unsigned short f2bf(float x) {
  union { float f; unsigned int u; } c; c.f = x;
  unsigned int r = c.u + 0x7fffu + ((c.u >> 16) & 1u);
  return (unsigned short)(r >> 16);
}

// ================= dispatch A: norm2(256) | norm3(64) =================
// Writes A/P in MFMA-fragment-contiguous (swizzled) layout:
//   slot(row,c) = (row>>4)*2048 + (c>>5)*512 + (((c>>3)&3)*16 + (row&15))*8 + (c&7)
// so an nce wave's k-th fragment load is tile_base + k*512 + lane*8 (1 KB contiguous).
__device__ void norm_body(char* smem, const float* __restrict__ emb, int L,
                          unsigned short* __restrict__ Abf, unsigned short* __restrict__ Pbf,
                          int b, int l0) {
  float (*tile)[33] = (float(*)[33])smem;                 // 128*33*4 = 16896 B
  float (*np8)[32]  = (float(*)[32])(smem + 16896);       // 1024 B
  float* scl        = (float*)(smem + 16896 + 1024);      // 128 B
  int tid = threadIdx.x;
  int lx = tid & 31, cq = tid >> 5;
  const float* eb = emb + (size_t)b * 128 * L + l0;
  for (int c = cq; c < 128; c += 8) tile[c][lx] = eb[(size_t)c * L + lx];
  __syncthreads();
  {
    float s = 0.f;
    for (int c = cq; c < 128; c += 8) { float x = tile[c][lx]; s += x * x; }
    np8[cq][lx] = s;
  }
  __syncthreads();
  if (tid < 32) {
    float t = 0.f;
#pragma unroll
    for (int g = 0; g < 8; ++g) t += np8[g][tid];
    float nrm = fmaxf(sqrtf(t), 1e-12f);
    scl[tid] = ((tid & 1) ? 1.0f : SA_SCALE) / nrm;  // even l -> anchor (scaled)
  }
  __syncthreads();
  int c = tid & 127, lh = tid >> 7;
  int half = L >> 1;
  int k = c >> 5, quad = (c >> 3) & 3, j = c & 7;
  for (int lp = lh; lp < 32; lp += 2) {
    int l = l0 + lp;
    int row = b * half + (l >> 1);
    unsigned short v = f2bf(tile[c][lp] * scl[lp]);
    unsigned short* dst = (l & 1) ? Pbf : Abf;
    dst[(size_t)(row >> 4) * 2048 + k * 512 + ((quad << 4) + (row & 15)) * 8 + j] = v;
  }
}

__global__ void __launch_bounds__(256) fusedA_kernel(const float* __restrict__ c2,
                                                     const float* __restrict__ c3,
                                                     char* __restrict__ ws) {
  extern __shared__ char smem[];
  int bid = blockIdx.x;
  if (bid < 256) {
    norm_body(smem, c2, 1024, (unsigned short*)(ws + O_A2), (unsigned short*)(ws + O_P2),
              bid & 7, (bid >> 3) * 32);
  } else {
    int nb = bid - 256;
    norm_body(smem, c3, 256, (unsigned short*)(ws + O_A3), (unsigned short*)(ws + O_P3),
              nb & 7, (nb >> 3) * 32);
  }
}

// ================= dispatch B: word(512) | nce2(2048) | nce3(512) | ce(1024) =================
__device__ void word_body(char* smem, const float* __restrict__ wp,
                          const float* __restrict__ cf,
                          const int* __restrict__ targets,
                          char* __restrict__ ws, int w) {
  int* sc      = (int*)smem;              // 1024 B
  int* splist  = (int*)(smem + 1024);     // 4096 B
  int* snext_sh = (int*)(smem + 5120);    // 4 B
  float* wacc  = (float*)(smem + 5124);   // 16 B
  int tid = threadIdx.x;
  int z = w & 15, tq = (w >> 4) & 3, b = w >> 6;
  const int* tb = targets + b * 4096;
  int tbase = tq * 1024;
  int4 tok = ((const int4*)(tb + tbase))[tid];
  int f0 = (tok.x == SPACE_TOK), f1 = (tok.y == SPACE_TOK),
      f2 = (tok.z == SPACE_TOK), f3 = (tok.w == SPACE_TOK);
  int cnt = f0 + f1 + f2 + f3;
  sc[tid] = cnt;
  __syncthreads();
  for (int off = 1; off < 256; off <<= 1) {
    int v = (tid >= off) ? sc[tid - off] : 0;
    __syncthreads();
    sc[tid] += v;
    __syncthreads();
  }
  int base = sc[tid] - cnt;
  int p = tbase + tid * 4;
  if (f0) splist[base++] = p;
  if (f1) splist[base++] = p + 1;
  if (f2) splist[base++] = p + 2;
  if (f3) splist[base++] = p + 3;
  int m = sc[255];
  if (tid == 0) *snext_sh = -1;
  __syncthreads();
  if (m > 0) {
    for (int wstart = tbase + 1024; wstart < 4096 && *snext_sh < 0; wstart += 1024) {
      int t = wstart + tid * 4;
      int4 tk = ((const int4*)tb)[t >> 2];
      int found = 0x7fffffff;
      if (tk.x == SPACE_TOK) found = t;
      else if (tk.y == SPACE_TOK) found = t + 1;
      else if (tk.z == SPACE_TOK) found = t + 2;
      else if (tk.w == SPACE_TOK) found = t + 3;
#pragma unroll
      for (int mm = 1; mm < 64; mm <<= 1) found = min(found, __shfl_xor(found, mm));
      if ((tid & 63) == 0) sc[tid >> 6] = found;
      __syncthreads();
      if (tid == 0) {
        int f = min(min(sc[0], sc[1]), min(sc[2], sc[3]));
        if (f != 0x7fffffff) *snext_sh = f;
      }
      __syncthreads();
    }
  }
  int snext = *snext_sh;
  int wave = tid >> 6, lane = tid & 63;
  int dbase = z * 32 + wave * 8;
  const float* r0 = cf + ((size_t)(b * 512 + dbase)) * 4096;
  float myacc = 0.f;
  float lcnt = 0.f;
  for (int i = 0; i < m; ++i) {
    int t0 = splist[i];
    int t1 = (i + 1 < m) ? splist[i + 1] : snext;
    if (t1 < 0) break;
    int seglen = t1 - t0 - 1;
    if (seglen <= 0) continue;
    lcnt += 1.0f;
    int wpos = t0 >> 1;
    float invc = 1.0f / (float)seglen;
    int c0 = (t0 + 1) >> 2;
    int c1 = (t1 + 3) >> 2;
    float s0 = 0.f, s1 = 0.f, s2 = 0.f, s3 = 0.f, s4 = 0.f, s5 = 0.f, s6 = 0.f, s7 = 0.f;
    for (int c = c0 + lane; c < c1; c += 64) {
      int tbp = c << 2;
      float4 v0 = *(const float4*)(r0 + 0 * 4096 + tbp);
      float4 v1 = *(const float4*)(r0 + 1 * 4096 + tbp);
      float4 v2 = *(const float4*)(r0 + 2 * 4096 + tbp);
      float4 v3 = *(const float4*)(r0 + 3 * 4096 + tbp);
      float4 v4 = *(const float4*)(r0 + 4 * 4096 + tbp);
      float4 v5 = *(const float4*)(r0 + 5 * 4096 + tbp);
      float4 v6 = *(const float4*)(r0 + 6 * 4096 + tbp);
      float4 v7 = *(const float4*)(r0 + 7 * 4096 + tbp);
      float m0 = (tbp + 0 > t0 && tbp + 0 < t1) ? 1.f : 0.f;
      float m1 = (tbp + 1 > t0 && tbp + 1 < t1) ? 1.f : 0.f;
      float m2 = (tbp + 2 > t0 && tbp + 2 < t1) ? 1.f : 0.f;
      float m3 = (tbp + 3 > t0 && tbp + 3 < t1) ? 1.f : 0.f;
      s0 += v0.x * m0 + v0.y * m1 + v0.z * m2 + v0.w * m3;
      s1 += v1.x * m0 + v1.y * m1 + v1.z * m2 + v1.w * m3;
      s2 += v2.x * m0 + v2.y * m1 + v2.z * m2 + v2.w * m3;
      s3 += v3.x * m0 + v3.y * m1 + v3.z * m2 + v3.w * m3;
      s4 += v4.x * m0 + v4.y * m1 + v4.z * m2 + v4.w * m3;
      s5 += v5.x * m0 + v5.y * m1 + v5.z * m2 + v5.w * m3;
      s6 += v6.x * m0 + v6.y * m1 + v6.z * m2 + v6.w * m3;
      s7 += v7.x * m0 + v7.y * m1 + v7.z * m2 + v7.w * m3;
    }
#pragma unroll
    for (int mm = 1; mm < 64; mm <<= 1) {
      s0 += __shfl_xor(s0, mm); s1 += __shfl_xor(s1, mm);
      s2 += __shfl_xor(s2, mm); s3 += __shfl_xor(s3, mm);
      s4 += __shfl_xor(s4, mm); s5 += __shfl_xor(s5, mm);
      s6 += __shfl_xor(s6, mm); s7 += __shfl_xor(s7, mm);
    }
    if (lane < 8) {
      float sv = (lane == 0) ? s0 : (lane == 1) ? s1 : (lane == 2) ? s2 : (lane == 3) ? s3
               : (lane == 4) ? s4 : (lane == 5) ? s5 : (lane == 6) ? s6 : s7;
      float mean = sv * invc;
      float pred = wp[((size_t)(b * 512 + dbase + lane)) * 2048 + wpos];
      float diff = pred - mean;
      myacc += diff * diff;
    }
  }
#pragma unroll
  for (int mm = 1; mm < 8; mm <<= 1) myacc += __shfl_xor(myacc, mm);
  if (lane == 0) wacc[wave] = myacc;
  __syncthreads();
  if (tid == 0) {
    ((float*)(ws + O_WPART))[w] = (wacc[0] + wacc[1] + wacc[2] + wacc[3]) * (1.0f / 512.0f);
    if (z == 0) ((float*)(ws + O_WCNT))[w >> 4] = lcnt;
  }
}

// nce: swizzled fragment loads — every global load is 64 lanes x 16 B contiguous.
__device__ void nce_body(char* smem, const unsigned short* __restrict__ A,
                         const unsigned short* __restrict__ P, int n, int sliceJ,
                         int blk_i, int s, float* __restrict__ pexp,
                         float* __restrict__ diag) {
  int tid = threadIdx.x;
  int wave = tid >> 6, lane = tid & 63;
  int col = lane & 15, quad = lane >> 4;
  int I0 = blk_i * 16;
  const unsigned short* At = A + (size_t)blk_i * 2048 + lane * 8;
  bf16x8 a0 = *(const bf16x8*)(At);
  bf16x8 a1 = *(const bf16x8*)(At + 512);
  bf16x8 a2 = *(const bf16x8*)(At + 1024);
  bf16x8 a3 = *(const bf16x8*)(At + 1536);
  float rl0 = 0.f, rl1 = 0.f, rl2 = 0.f, rl3 = 0.f;
  float dcap = 0.f;
  int perW = sliceJ >> 2;
  int J0w = s * sliceJ + wave * perW, Jend = J0w + perW;
#pragma unroll 2
  for (int J = J0w; J < Jend; J += 16) {
    const unsigned short* Pt = P + (size_t)(J >> 4) * 2048 + lane * 8;
    bf16x8 b0 = *(const bf16x8*)(Pt);
    bf16x8 b1 = *(const bf16x8*)(Pt + 512);
    bf16x8 b2 = *(const bf16x8*)(Pt + 1024);
    bf16x8 b3 = *(const bf16x8*)(Pt + 1536);
    f32x4 cfr = {0.f, 0.f, 0.f, 0.f};
    cfr = __builtin_amdgcn_mfma_f32_16x16x32_bf16(a0, b0, cfr, 0, 0, 0);
    cfr = __builtin_amdgcn_mfma_f32_16x16x32_bf16(a1, b1, cfr, 0, 0, 0);
    cfr = __builtin_amdgcn_mfma_f32_16x16x32_bf16(a2, b2, cfr, 0, 0, 0);
    cfr = __builtin_amdgcn_mfma_f32_16x16x32_bf16(a3, b3, cfr, 0, 0, 0);
    rl0 += exp2f(cfr[0] - SA_SCALE);
    rl1 += exp2f(cfr[1] - SA_SCALE);
    rl2 += exp2f(cfr[2] - SA_SCALE);
    rl3 += exp2f(cfr[3] - SA_SCALE);
    if (J == I0) {
      int r = col - (quad << 2);
      if (r == 0) dcap = cfr[0];
      else if (r == 1) dcap = cfr[1];
      else if (r == 2) dcap = cfr[2];
      else if (r == 3) dcap = cfr[3];
    }
  }
  float (*part)[16][17] = (float(*)[16][17])smem;          // padded: no 4-way conflict
  float (*dpart)[16]    = (float(*)[16])(smem + 4352);
  part[wave][(quad << 2) + 0][col] = rl0;
  part[wave][(quad << 2) + 1][col] = rl1;
  part[wave][(quad << 2) + 2][col] = rl2;
  part[wave][(quad << 2) + 3][col] = rl3;
  if (quad == (col >> 2)) dpart[wave][col] = dcap;
  __syncthreads();
  {
    int rrow = tid >> 4, cc = tid & 15;
    float sv = 0.f, d = 0.f;
#pragma unroll
    for (int ww = 0; ww < 4; ++ww) { sv += part[ww][rrow][cc]; d += dpart[ww][rrow]; }
#pragma unroll
    for (int mm = 1; mm < 16; mm <<= 1) sv += __shfl_xor(sv, mm);
    if (cc == 0) {
      pexp[I0 + rrow] = sv;
      if (I0 >= s * sliceJ && I0 < (s + 1) * sliceJ) diag[I0 + rrow] = d;
    }
  }
}

__device__ void ce_body(char* smem, const float* __restrict__ logits,
                        const int* __restrict__ targets, const float* __restrict__ mask,
                        char* ws, int cb) {
  int tid = threadIdx.x;
  int wave = tid >> 6, lane = tid & 63;
  int rbase = cb * 32 + wave * 8;
  float4 v[8];
  float mk[8];
  int tg[8];
#pragma unroll
  for (int rr = 0; rr < 8; ++rr) v[rr] = ((const float4*)logits)[(size_t)(rbase + rr) * 64 + lane];
#pragma unroll
  for (int rr = 0; rr < 8; ++rr) { tg[rr] = targets[rbase + rr]; mk[rr] = mask[rbase + rr]; }
  float aCM = 0.f, aM = 0.f, aC = 0.f;
#pragma unroll
  for (int rr = 0; rr < 8; ++rr) {
    float e = __expf(v[rr].x) + __expf(v[rr].y) + __expf(v[rr].z) + __expf(v[rr].w);
#pragma unroll
    for (int m = 1; m < 64; m <<= 1) e += __shfl_xor(e, m);
    int t = tg[rr];
    int q = t & 3;
    float sel = (q == 0) ? v[rr].x : (q == 1) ? v[rr].y : (q == 2) ? v[rr].z : v[rr].w;
    float xt = __shfl(sel, t >> 2);
    float ce = __logf(e) - xt;
    aCM += ce * mk[rr]; aM += mk[rr]; aC += ce;
  }
  float (*red)[3] = (float(*)[3])smem;
  if (lane == 0) { red[wave][0] = aCM; red[wave][1] = aM; red[wave][2] = aC; }
  __syncthreads();
  if (tid == 0) {
    ((float*)(ws + O_CECM))[cb] = red[0][0] + red[1][0] + red[2][0] + red[3][0];
    ((float*)(ws + O_CEM ))[cb] = red[0][1] + red[1][1] + red[2][1] + red[3][1];
    ((float*)(ws + O_CEC ))[cb] = red[0][2] + red[1][2] + red[2][2] + red[3][2];
  }
}

__global__ void __launch_bounds__(256) fusedB_kernel(const float* __restrict__ logits,
                                                     const float* __restrict__ wp,
                                                     const float* __restrict__ cf,
                                                     const int* __restrict__ targets,
                                                     const float* __restrict__ mask,
                                                     char* __restrict__ ws) {
  extern __shared__ char smem[];
  int bid = blockIdx.x;
  if (bid < 512) {
    word_body(smem, wp, cf, targets, ws, bid);
  } else if (bid < 2560) {
    int nb = bid - 512;
    nce_body(smem, (const unsigned short*)(ws + O_A2), (const unsigned short*)(ws + O_P2),
             4096, 512, nb >> 3, nb & 7,
             (float*)(ws + O_PEXP2) + (nb & 7) * 4096, (float*)(ws + O_DIAG2));
  } else if (bid < 3072) {
    int nb = bid - 2560;
    nce_body(smem, (const unsigned short*)(ws + O_A3), (const unsigned short*)(ws + O_P3),
             1024, 128, nb >> 3, nb & 7,
             (float*)(ws + O_PEXP3) + (nb & 7) * 1024, (float*)(ws + O_DIAG3));
  } else {
    ce_body(smem, logits, targets, mask, ws, bid - 3072);
  }
}

// ================= dispatch C: final tree-reduce + combine (vectorized) =================
__global__ void __launch_bounds__(256) final_kernel(const char* __restrict__ ws,
                                                    float* __restrict__ out) {
  int tid = threadIdx.x;
  int wave = tid >> 6, lane = tid & 63;
  float v[7] = {0.f, 0.f, 0.f, 0.f, 0.f, 0.f, 0.f};
  {
    float4 a = ((const float4*)(ws + O_CECM))[tid];
    float4 bb = ((const float4*)(ws + O_CEM))[tid];
    float4 c = ((const float4*)(ws + O_CEC))[tid];
    v[0] = a.x + a.y + a.z + a.w;
    v[1] = bb.x + bb.y + bb.z + bb.w;
    v[2] = c.x + c.y + c.z + c.w;
  }
  if (tid < 128) {
    float4 wv = ((const float4*)(ws + O_WPART))[tid];
    v[3] = wv.x + wv.y + wv.z + wv.w;
  }
  if (tid < 32) v[4] = ((const float*)(ws + O_WCNT))[tid];
  for (int r4 = tid; r4 < 1024; r4 += 256) {
    float4 S = {0.f, 0.f, 0.f, 0.f};
#pragma unroll
    for (int s = 0; s < 8; ++s) {
      float4 pv = ((const float4*)(ws + O_PEXP2))[s * 1024 + r4];
      S.x += pv.x; S.y += pv.y; S.z += pv.z; S.w += pv.w;
    }
    float4 dg = ((const float4*)(ws + O_DIAG2))[r4];
    v[5] += 4.0f * INV_T + __logf(S.x) + __logf(S.y) + __logf(S.z) + __logf(S.w)
            - LN2F * (dg.x + dg.y + dg.z + dg.w);
  }
  {
    int r4 = tid;
    float4 S = {0.f, 0.f, 0.f, 0.f};
#pragma unroll
    for (int s = 0; s < 8; ++s) {
      float4 pv = ((const float4*)(ws + O_PEXP3))[s * 256 + r4];
      S.x += pv.x; S.y += pv.y; S.z += pv.z; S.w += pv.w;
    }
    float4 dg = ((const float4*)(ws + O_DIAG3))[r4];
    v[6] = 4.0f * INV_T + __logf(S.x) + __logf(S.y) + __logf(S.z) + __logf(S.w)
           - LN2F * (dg.x + dg.y + dg.z + dg.w);
  }
#pragma unroll
  for (int j = 0; j < 7; ++j) {
    float x = v[j];
#pragma unroll
    for (int mm = 1; mm < 64; mm <<= 1) x += __shfl_xor(x, mm);
    v[j] = x;
  }
  __shared__ float fr[4][7];
  if (lane == 0)
#pragma unroll
    for (int j = 0; j < 7; ++j) fr[wave][j] = v[j];
  __syncthreads();
  if (tid == 0) {
    float s[7];
#pragma unroll
    for (int j = 0; j < 7; ++j) s[j] = fr[0][j] + fr[1][j] + fr[2][j] + fr[3][j];
    float n = s[1];
    float charL = (n > 0.f) ? (s[0] / fmaxf(n, 1.f)) : (s[2] / 32768.0f);
    float wordL = (s[4] > 0.f) ? (s[3] / fmaxf(s[4], 1.f)) : 0.f;
    out[0] = charL + 0.5f * wordL + 0.1f * (s[5] / 4096.0f) + 0.1f * (s[6] / 1024.0f);
  }
}

extern "C" void kernel_launch(void* const* d_in, const int* in_sizes, int n_in,
                              void* d_out, int out_size, void* d_ws, size_t ws_size,
                              hipStream_t stream) {
  (void)in_sizes; (void)n_in; (void)out_size; (void)ws_size;
  const float* logits        = (const float*)d_in[0];
  const float* word_preds    = (const float*)d_in[1];
  const float* char_features = (const float*)d_in[2];
  const float* c2            = (const float*)d_in[3];
  const float* c3            = (const float*)d_in[4];
  const int*   targets       = (const int*)d_in[5];
  const float* mask          = (const float*)d_in[6];
  float* out = (float*)d_out;
  char* ws = (char*)d_ws;

  fusedA_kernel<<<320, 256, SMEM_A, stream>>>(c2, c3, ws);
  fusedB_kernel<<<4096, 256, SMEM_B, stream>>>(logits, word_preds, char_features,
                                               targets, mask, ws);
  final_kernel<<<1, 256, 0, stream>>>(ws, out);
}